// Round 8
// baseline (1503.269 us; speedup 1.0000x reference)
//
#include <hip/hip_runtime.h>
#include <stdint.h>
#include <stddef.h>

// ---------------------------------------------------------------------------
// BoundingBox loss processor:
//   filter (maxconf > 0.6) -> sort by class-0 score desc (stable, idx asc)
//   -> greedy NMS (IoU > 0.5 suppress) -> per-class top-20 over kept
//   -> smooth-L1 vs targets + focal CE on (class0 top-20 > 0.5) -> /M
// ---------------------------------------------------------------------------

#define NCAP 8192
#define WROW (NCAP / 64)   // 128 u64 words per mask row
#define GBATCH 32          // gather rows per vmcnt batch (32 KB LDS stage)

typedef unsigned long long u64;

// ---------------- workspace layout (all offsets 16-byte aligned) -----------
constexpr size_t OFF_CNT   = 0;                               // 2 x u32: [0]=F, [1]=M
constexpr size_t OFF_KEYS  = 256;                             // u64[NCAP]
constexpr size_t OFF_SX1   = OFF_KEYS + 8ull * NCAP;          // f32[NCAP]
constexpr size_t OFF_SY1   = OFF_SX1 + 4ull * NCAP;
constexpr size_t OFF_SX2   = OFF_SY1 + 4ull * NCAP;
constexpr size_t OFF_SY2   = OFF_SX2 + 4ull * NCAP;
constexpr size_t OFF_AREA  = OFF_SY2 + 4ull * NCAP;
constexpr size_t OFF_SORIG = OFF_AREA + 4ull * NCAP;          // u32[NCAP]
constexpr size_t OFF_KEEPS = OFF_SORIG + 4ull * NCAP;         // u32[NCAP]
constexpr size_t OFF_KORIG = OFF_KEEPS + 4ull * NCAP;         // u32[NCAP]
constexpr size_t OFF_TOPV  = OFF_KORIG + 4ull * NCAP;         // f32[1024]
constexpr size_t OFF_TOPI  = OFF_TOPV + 4096;                 // i32[1024]
constexpr size_t OFF_DIAG  = OFF_TOPI + 4096;                 // u64[NCAP+128] (+pad for prefetch overread)
constexpr size_t OFF_MASK  = OFF_DIAG + 8ull * (NCAP + 128);  // u64[NCAP*WROW] = 8 MB
constexpr size_t WS_NEED_MASK = OFF_MASK + 8ull * NCAP * WROW;

// ---- single-wave DMA helpers (global -> LDS, no destination registers) ----
// gfx9 semantics: LDS dest = M0 + lane*16; per-lane global addr; exec-masked
// lanes skip. vmcnt-tracked; "memory" clobber orders vs later ds_reads.
__device__ __forceinline__ void gll16(const void* g, unsigned lds_off) {
  asm volatile("s_mov_b32 m0, %1\n\t"
               "global_load_lds_dwordx4 %0, off"
               :: "v"(g), "s"(lds_off) : "memory");
}
__device__ __forceinline__ void wait_vm0() {
  asm volatile("s_waitcnt vmcnt(0)" ::: "memory");
}
__device__ __forceinline__ u64 rdl64(u64 x, int l) {
  unsigned lo = __builtin_amdgcn_readlane((unsigned)x, l);
  unsigned hi = __builtin_amdgcn_readlane((unsigned)(x >> 32), l);
  return ((u64)hi << 32) | lo;
}

// ---------------- kernels ---------------------------------------------------

// Per row: valid = max over C confs > 0.6; sort key = desc(class0 score) | row.
__global__ void k_filter(const float* __restrict__ conf, int N, int C,
                         u64* __restrict__ keys) {
  int row = blockIdx.x * blockDim.x + threadIdx.x;
  if (row >= NCAP) return;
  u64 key;
  if (row < N) {
    const float* cr = conf + (size_t)row * C;
    float mx = cr[0];
    for (int c = 1; c < C; ++c) mx = fmaxf(mx, cr[c]);
    unsigned int k32;
    if (mx > 0.6f) {
      union { float f; unsigned int u; } s; s.f = cr[0];
      unsigned int u = s.u;
      // monotone float->uint (ascending), then invert for descending sort
      u = (u & 0x80000000u) ? ~u : (u | 0x80000000u);
      k32 = ~u;
      if (k32 == 0xFFFFFFFFu) k32 = 0xFFFFFFFEu;  // keep 0xFFFFFFFF = invalid
    } else {
      k32 = 0xFFFFFFFFu;  // invalid rows sort last
    }
    key = ((u64)k32 << 32) | (unsigned int)row;
  } else {
    key = ((u64)0xFFFFFFFFu << 32);  // pad
  }
  keys[row] = key;
}

// One-block LDS bitonic sort, ascending u64 (desc score, asc row on ties).
// Epilogue counts valid rows (high32 != 0xFFFFFFFF) -> cnt[0] (replaces k_init
// + k_filter atomics: one fewer dispatch).
__global__ __launch_bounds__(1024) void k_sort(u64* __restrict__ keys,
                                               unsigned int* __restrict__ cnt) {
  __shared__ u64 sk[NCAP];  // 64 KiB
  __shared__ int redc[1024];
  int tid = threadIdx.x;
  for (int t = tid; t < NCAP; t += 1024) sk[t] = keys[t];
  __syncthreads();
  for (unsigned int k = 2; k <= NCAP; k <<= 1) {
    for (unsigned int j = k >> 1; j > 0; j >>= 1) {
      for (int t = tid; t < NCAP; t += 1024) {
        unsigned int p = (unsigned int)t ^ j;
        if (p > (unsigned int)t) {
          bool up = ((t & k) == 0);
          u64 x = sk[t], y = sk[p];
          bool sw = up ? (x > y) : (x < y);
          if (sw) { sk[t] = y; sk[p] = x; }
        }
      }
      __syncthreads();
    }
  }
  int cv = 0;
  for (int t = tid; t < NCAP; t += 1024) {
    keys[t] = sk[t];
    if ((sk[t] >> 32) != 0xFFFFFFFFull) ++cv;
  }
  redc[tid] = cv;
  __syncthreads();
  for (int s = 512; s > 0; s >>= 1) {
    if (tid < s) redc[tid] += redc[tid + s];
    __syncthreads();
  }
  if (tid == 0) cnt[0] = (unsigned int)redc[0];
}

// Gather boxes into sorted order, precompute areas.
__global__ void k_gather(const float* __restrict__ loc,
                         const u64* __restrict__ keys,
                         float* __restrict__ sx1, float* __restrict__ sy1,
                         float* __restrict__ sx2, float* __restrict__ sy2,
                         float* __restrict__ sarea, unsigned int* __restrict__ sorig) {
  int p = blockIdx.x * blockDim.x + threadIdx.x;
  if (p >= NCAP) return;
  unsigned int row = (unsigned int)(keys[p] & 0xFFFFFFFFull);
  const float* b = loc + (size_t)row * 4;
  float x1 = b[0], y1 = b[1], x2 = b[2], y2 = b[3];
  sx1[p] = x1; sy1[p] = y1; sx2[p] = x2; sy2[p] = y2;
  sarea[p] = (x2 - x1) * (y2 - y1);   // numpy op order, no FMA hazard
  sorig[p] = row;
}

// Pairwise IoU>0.5 bitmask, 64x64 tiles, 1 wave per block.
// Lower-triangle blocks (by < bx) never consumed -> skipped. Diagonal blocks
// also write the compact diagG[] strip (one u64 per row) for k_scan's greedy.
__global__ __launch_bounds__(64) void k_mask(
    const float* __restrict__ sx1, const float* __restrict__ sy1,
    const float* __restrict__ sx2, const float* __restrict__ sy2,
    const float* __restrict__ sarea,
    u64* __restrict__ mask, u64* __restrict__ diagG) {
  if (blockIdx.y < blockIdx.x) return;
  __shared__ float jx1[64], jy1[64], jx2[64], jy2[64], ja[64];
  int t = threadIdx.x;
  int jbase = blockIdx.y * 64;
  jx1[t] = sx1[jbase + t]; jy1[t] = sy1[jbase + t];
  jx2[t] = sx2[jbase + t]; jy2[t] = sy2[jbase + t];
  ja[t]  = sarea[jbase + t];
  __syncthreads();
  int i = blockIdx.x * 64 + t;
  float xi1 = sx1[i], yi1 = sy1[i], xi2 = sx2[i], yi2 = sy2[i], ai = sarea[i];
  u64 bits = 0ULL;
#pragma unroll 8
  for (int jj = 0; jj < 64; ++jj) {
    float xx1 = fmaxf(xi1, jx1[jj]);
    float yy1 = fmaxf(yi1, jy1[jj]);
    float xx2 = fminf(xi2, jx2[jj]);
    float yy2 = fminf(yi2, jy2[jj]);
    float w = fmaxf(xx2 - xx1, 0.0f);
    float h = fmaxf(yy2 - yy1, 0.0f);
    float inter = w * h;
    float den = ai + ja[jj] - inter;   // (ai + aj) - inter, numpy order
    float iou = inter / den;           // IEEE div; 0/0 -> NaN -> compare false
    if (iou > 0.5f) bits |= (1ULL << jj);
  }
  mask[(size_t)i * WROW + blockIdx.y] = bits;
  if (blockIdx.x == blockIdx.y) diagG[i] = bits;
}

// ---------------------------------------------------------------------------
// Greedy scan: ONE wave, ZERO barriers. Removed-set in registers (2 u64/lane:
// lane l owns mask words 2l, 2l+1). Per 64-row chunk h:
//   greedy: diag words from LDS (DMA-prefetched last chunk), sup word via
//     readlane from the register bitset; ctz + 2-readlane chain per keep.
//   gather: kept rows' mask words DMA'd global->LDS via global_load_lds
//     (NO destination registers -> compiler cannot serialize or spill; the
//     failure mode of rounds 2-7), ONE s_waitcnt vmcnt(0), then ds_read_b128
//     + OR into the register bitset. Diag for h+1 prefetched in the same
//     batch -> exactly one exposed memory latency per chunk.
// ---------------------------------------------------------------------------
__global__ __launch_bounds__(64) void k_scan(
    const u64* __restrict__ mask,
    const u64* __restrict__ diagG,
    unsigned int* __restrict__ cnt,
    unsigned int* __restrict__ keeps) {
  __shared__ u64 dbuf[2][128];         // 2 x 1KB diag staging (64 lanes x 16B)
  __shared__ u64 stage[GBATCH * 128];  // 32 rows x 1KB gather staging
  const int lane = threadIdx.x;
  const int F = (int)cnt[0];
  const int nch = (F + 63) >> 6;
  const unsigned dbufOff = (unsigned)(uintptr_t)&dbuf[0][0];   // LDS byte offset
  const unsigned stageOff = (unsigned)(uintptr_t)&stage[0];
  u64 rem0 = 0, rem1 = 0;
  int K = 0;

  if (nch > 0) {
    gll16(diagG + 2 * lane, dbufOff);   // chunk 0 diag (first 64 u64 used)
    wait_vm0();
    for (int h = 0; h < nch; ++h) {
      const int base = h << 6;
      // ---- greedy (all in-wave) ----
      u64 D = dbuf[h & 1][lane];
      u64 sel = (h & 1) ? rem1 : rem0;
      u64 sup = rdl64(sel, h >> 1);
      int remrows = F - base;
      u64 valid = (remrows >= 64) ? ~0ull : ((1ull << remrows) - 1ull);
      u64 undec = valid & ~sup;
      u64 keep = 0;
      while (undec) {
        int rr = __builtin_ctzll(undec);
        rr = __builtin_amdgcn_readfirstlane(rr);
        keep |= 1ull << rr;
        u64 Dr = rdl64(D, rr);
        // clear rr itself: degenerate boxes can give NaN self-IoU
        undec &= ~(Dr | (1ull << rr));
      }
      // parallel keeps store (prefix via mbcnt)
      unsigned klo = (unsigned)keep, khi = (unsigned)(keep >> 32);
      int pre = __builtin_amdgcn_mbcnt_hi(khi, __builtin_amdgcn_mbcnt_lo(klo, 0));
      if ((keep >> lane) & 1ull) keeps[K + pre] = (unsigned)(base + lane);
      K += __popcll(keep);

      // ---- prefetch next chunk's diag (lands by this chunk's wait) ----
      int hn = (h + 1 < nch) ? h + 1 : h;
      gll16(diagG + (hn << 6) + 2 * lane, dbufOff + ((unsigned)((h + 1) & 1)) * 1024);

      // ---- gather kept rows' words (lane's words 2l,2l+1; only l>=h/2 matter) ----
      const bool wpred = (lane >= (h >> 1));
      u64 kk = keep;
      do {
        u64 kb = 0;
        { u64 t = kk; int bn = 0;
          while (t && bn < GBATCH) { int r2 = __builtin_ctzll(t); t &= t - 1; kb |= 1ull << r2; ++bn; } }
        kk &= ~kb;
        if (wpred) {
          u64 t = kb; unsigned j = 0;
          while (t) {
            int r2 = __builtin_ctzll(t); t &= t - 1;
            r2 = __builtin_amdgcn_readfirstlane(r2);
            gll16(mask + (size_t)(base + r2) * WROW + 2 * lane, stageOff + j * 1024u);
            ++j;
          }
        }
        wait_vm0();   // one drain: all row DMAs + diag prefetch
        if (wpred) {
          u64 t = kb; int j = 0;
          while (t) {
            int r2 = __builtin_ctzll(t); t &= t - 1; (void)r2;
            ulonglong2 v = *(const ulonglong2*)&stage[j * 128 + 2 * lane];
            rem0 |= v.x; rem1 |= v.y;
            ++j;
          }
        }
      } while (kk);
    }
  }
  if (lane == 0) cnt[1] = (unsigned int)K;
}

// Fallback (small workspace): on-the-fly IoU greedy scan in one block.
__global__ __launch_bounds__(256) void k_scan_nomask(
    const float* __restrict__ sx1, const float* __restrict__ sy1,
    const float* __restrict__ sx2, const float* __restrict__ sy2,
    const float* __restrict__ sarea,
    unsigned int* __restrict__ cnt,
    unsigned int* __restrict__ keeps) {
  __shared__ unsigned char sup[NCAP];
  __shared__ int sK;
  int tid = threadIdx.x;
  int F = (int)cnt[0];
  for (int j = tid; j < NCAP; j += 256) sup[j] = 0;
  if (tid == 0) sK = 0;
  __syncthreads();
  for (int i = 0; i < F; ++i) {
    if (!sup[i]) {
      if (tid == 0) keeps[sK++] = (unsigned int)i;
      float xi1 = sx1[i], yi1 = sy1[i], xi2 = sx2[i], yi2 = sy2[i], ai = sarea[i];
      for (int j = i + 1 + tid; j < F; j += 256) {
        if (sup[j]) continue;
        float xx1 = fmaxf(xi1, sx1[j]);
        float yy1 = fmaxf(yi1, sy1[j]);
        float xx2 = fminf(xi2, sx2[j]);
        float yy2 = fminf(yi2, sy2[j]);
        float w = fmaxf(xx2 - xx1, 0.0f);
        float h = fmaxf(yy2 - yy1, 0.0f);
        float inter = w * h;
        float iou = inter / (ai + sarea[j] - inter);
        if (iou > 0.5f) sup[j] = 1;
      }
    }
    __syncthreads();
  }
  if (tid == 0) cnt[1] = (unsigned int)sK;
}

// kept (sorted-space) -> original row indices
__global__ void k_keptorig(const unsigned int* __restrict__ sorig,
                           const unsigned int* __restrict__ keeps,
                           unsigned int* __restrict__ korig,
                           const unsigned int* __restrict__ cnt) {
  int j = blockIdx.x * blockDim.x + threadIdx.x;
  if (j < (int)cnt[1]) korig[j] = sorig[keeps[j]];
}

// Per class (block), top-KT over the M kept boxes; lax.top_k tie semantics.
__global__ __launch_bounds__(256) void k_topk(
    const float* __restrict__ conf,
    const unsigned int* __restrict__ korig,
    const unsigned int* __restrict__ cnt,
    int C, int KT,
    float* __restrict__ topv, int* __restrict__ topi) {
  __shared__ float col[NCAP];
  __shared__ unsigned char flags[NCAP];
  __shared__ float rv[256];
  __shared__ int ri[256];
  int tid = threadIdx.x;
  int c = blockIdx.x;
  int M = (int)cnt[1];
  for (int j = tid; j < M; j += 256) {
    col[j] = conf[(size_t)korig[j] * C + c];
    flags[j] = 0;
  }
  __syncthreads();
  for (int t = 0; t < KT; ++t) {
    float bv = -3.402823466e+38f;
    int bj = 0x7FFFFFFF;
    for (int j = tid; j < M; j += 256) {
      if (flags[j]) continue;
      float v = col[j];
      if (v > bv || (v == bv && j < bj)) { bv = v; bj = j; }
    }
    rv[tid] = bv; ri[tid] = bj;
    __syncthreads();
    for (int ss = 128; ss > 0; ss >>= 1) {
      if (tid < ss) {
        float v2 = rv[tid + ss]; int j2 = ri[tid + ss];
        if (v2 > rv[tid] || (v2 == rv[tid] && j2 < ri[tid])) { rv[tid] = v2; ri[tid] = j2; }
      }
      __syncthreads();
    }
    if (tid == 0) {
      int w = ri[0];
      if (w == 0x7FFFFFFF) w = 0;    // M < KT safety; reference would crash here
      else flags[w] = 1;
      topv[c * KT + t] = rv[0];
      topi[c * KT + t] = w;
    }
    __syncthreads();
  }
}

// Final scalar: smooth-L1 over (KT, C, 4) gathered boxes + focal CE on
// (class0 top-KT > 0.5), divided by M.
__global__ __launch_bounds__(256) void k_loss(
    const float* __restrict__ loc, const float* __restrict__ tb,
    const int* __restrict__ labels,
    const unsigned int* __restrict__ korig,
    const float* __restrict__ topv, const int* __restrict__ topi,
    const unsigned int* __restrict__ cnt, int C, int KT,
    float* __restrict__ out) {
  __shared__ float red[256];
  int tid = threadIdx.x;
  int F = (int)cnt[0];
  int M = (int)cnt[1];
  if (F == 0 || M == 0) {
    if (tid == 0) out[0] = 0.001f;
    return;
  }
  int total = KT * C * 4;
  float part = 0.0f;
  for (int e = tid; e < total; e += 256) {
    int d = e & 3;
    int q = e >> 2;
    int c = q % C;
    int i = q / C;
    int j = topi[c * KT + i];
    unsigned int orow = korig[j];
    float pred = loc[(size_t)orow * 4 + d];
    float tg = tb[c * 4 + d];
    float dd = fabsf(pred - tg);
    part += (dd < 1.0f) ? (0.5f * dd * dd) : (dd - 0.5f);
  }
  red[tid] = part;
  __syncthreads();
  for (int s = 128; s > 0; s >>= 1) {
    if (tid < s) red[tid] += red[tid + s];
    __syncthreads();
  }
  if (tid == 0) {
    float loc_loss = red[0];
    float mx = -3.402823466e+38f;
    for (int i = 0; i < KT; ++i) {
      float x = (topv[i] > 0.5f) ? 1.0f : 0.0f;   // class 0 column
      mx = fmaxf(mx, x);
    }
    float ssum = 0.0f;
    for (int i = 0; i < KT; ++i) {
      float x = (topv[i] > 0.5f) ? 1.0f : 0.0f;
      ssum += expf(x - mx);
    }
    float lse = mx + logf(ssum);
    float ce = 0.0f;
    for (int i = 0; i < KT; ++i) {
      float x = (topv[i] > 0.5f) ? 1.0f : 0.0f;
      ce += (float)labels[i] * (x - lse);
    }
    ce = -ce;
    float pt = expf(-ce);
    float om = 1.0f - pt;
    float conf_loss = 0.25f * om * om * ce;   // ALPHA=0.25, GAMMA=2
    out[0] = (loc_loss + conf_loss) / (float)M;
  }
}

// ---------------- host ------------------------------------------------------

extern "C" void kernel_launch(void* const* d_in, const int* in_sizes, int n_in,
                              void* d_out, int out_size, void* d_ws, size_t ws_size,
                              hipStream_t stream) {
  (void)n_in; (void)out_size;
  const float* loc    = (const float*)d_in[0];
  const float* conf   = (const float*)d_in[1];
  const float* tb     = (const float*)d_in[2];
  const int*   labels = (const int*)d_in[3];
  float* out = (float*)d_out;

  int N = in_sizes[0] / 4;
  if (N > NCAP) N = NCAP;
  int C  = (N > 0) ? (in_sizes[1] / N) : 20;
  int KT = in_sizes[3];

  char* ws = (char*)d_ws;
  unsigned int* cnt   = (unsigned int*)(ws + OFF_CNT);
  u64*          keys  = (u64*)(ws + OFF_KEYS);
  float*        sx1   = (float*)(ws + OFF_SX1);
  float*        sy1   = (float*)(ws + OFF_SY1);
  float*        sx2   = (float*)(ws + OFF_SX2);
  float*        sy2   = (float*)(ws + OFF_SY2);
  float*        sarea = (float*)(ws + OFF_AREA);
  unsigned int* sorig = (unsigned int*)(ws + OFF_SORIG);
  unsigned int* keeps = (unsigned int*)(ws + OFF_KEEPS);
  unsigned int* korig = (unsigned int*)(ws + OFF_KORIG);
  float*        topv  = (float*)(ws + OFF_TOPV);
  int*          topi  = (int*)(ws + OFF_TOPI);
  u64*          diagG = (u64*)(ws + OFF_DIAG);
  u64*          mask  = (u64*)(ws + OFF_MASK);

  bool use_mask = (ws_size >= WS_NEED_MASK);

  k_filter<<<NCAP / 256, 256, 0, stream>>>(conf, N, C, keys);
  k_sort<<<1, 1024, 0, stream>>>(keys, cnt);
  k_gather<<<NCAP / 256, 256, 0, stream>>>(loc, keys, sx1, sy1, sx2, sy2, sarea, sorig);
  if (use_mask) {
    k_mask<<<dim3(WROW, WROW), 64, 0, stream>>>(sx1, sy1, sx2, sy2, sarea, mask, diagG);
    k_scan<<<1, 64, 0, stream>>>(mask, diagG, cnt, keeps);
  } else {
    k_scan_nomask<<<1, 256, 0, stream>>>(sx1, sy1, sx2, sy2, sarea, cnt, keeps);
  }
  k_keptorig<<<NCAP / 256, 256, 0, stream>>>(sorig, keeps, korig, cnt);
  k_topk<<<C, 256, 0, stream>>>(conf, korig, cnt, C, KT, topv, topi);
  k_loss<<<1, 256, 0, stream>>>(loc, tb, labels, korig, topv, topi, cnt, C, KT, out);
}

// Round 9
// 973.792 us; speedup vs baseline: 1.5437x; 1.5437x over previous
//
#include <hip/hip_runtime.h>
#include <stdint.h>
#include <stddef.h>

// ---------------------------------------------------------------------------
// BoundingBox loss processor:
//   filter (maxconf > 0.6) -> sort by class-0 score desc (stable, idx asc)
//   -> greedy NMS (IoU > 0.5 suppress) -> per-class top-20 over kept
//   -> smooth-L1 vs targets + focal CE on (class0 top-20 > 0.5) -> /M
//
// NOTE (rounds 1-8): k_scan is the serial bottleneck; five structural
// variants plateau at ~600 us — consistent with a single-CU kernel running
// at reduced SCLK (~500 MHz), making the ~3500-keep serial chain the floor.
// This version pins k_scan at the empirically best structure (round 5) and
// trims dispatches/barriers elsewhere.
// ---------------------------------------------------------------------------

#define NCAP 8192
#define WROW (NCAP / 64)   // 128 u64 words per mask row

typedef unsigned long long u64;

// ---------------- workspace layout (all offsets 16-byte aligned) -----------
constexpr size_t OFF_CNT   = 0;                               // 2 x u32: [0]=F, [1]=M
constexpr size_t OFF_KEYS  = 256;                             // u64[NCAP]
constexpr size_t OFF_SX1   = OFF_KEYS + 8ull * NCAP;          // f32[NCAP]
constexpr size_t OFF_SY1   = OFF_SX1 + 4ull * NCAP;
constexpr size_t OFF_SX2   = OFF_SY1 + 4ull * NCAP;
constexpr size_t OFF_SY2   = OFF_SX2 + 4ull * NCAP;
constexpr size_t OFF_AREA  = OFF_SY2 + 4ull * NCAP;
constexpr size_t OFF_SORIG = OFF_AREA + 4ull * NCAP;          // u32[NCAP]
constexpr size_t OFF_KEEPS = OFF_SORIG + 4ull * NCAP;         // u32[NCAP]
constexpr size_t OFF_KORIG = OFF_KEEPS + 4ull * NCAP;         // u32[NCAP] (unused)
constexpr size_t OFF_TOPV  = OFF_KORIG + 4ull * NCAP;         // f32[1024]
constexpr size_t OFF_TOPI  = OFF_TOPV + 4096;                 // i32[1024]
constexpr size_t OFF_MASK  = OFF_TOPI + 4096;                 // u64[NCAP*WROW] = 8 MB
constexpr size_t WS_NEED_MASK = OFF_MASK + 8ull * NCAP * WROW;

// ---------------- kernels ---------------------------------------------------

// Fused filter + one-block LDS bitonic sort, ascending u64
// (desc class-0 score, asc row on ties). Keys computed from conf directly
// (was a separate k_filter dispatch). Epilogue counts valid rows -> cnt[0].
__global__ __launch_bounds__(1024) void k_sortf(
    const float* __restrict__ conf, int N, int C,
    u64* __restrict__ keys, unsigned int* __restrict__ cnt) {
  __shared__ u64 sk[NCAP];  // 64 KiB
  __shared__ int redc[1024];
  int tid = threadIdx.x;
  for (int row = tid; row < NCAP; row += 1024) {
    u64 key;
    if (row < N) {
      const float* cr = conf + (size_t)row * C;
      float mx = cr[0];
      for (int c = 1; c < C; ++c) mx = fmaxf(mx, cr[c]);
      unsigned int k32;
      if (mx > 0.6f) {
        union { float f; unsigned int u; } s; s.f = cr[0];
        unsigned int u = s.u;
        // monotone float->uint (ascending), then invert for descending sort
        u = (u & 0x80000000u) ? ~u : (u | 0x80000000u);
        k32 = ~u;
        if (k32 == 0xFFFFFFFFu) k32 = 0xFFFFFFFEu;  // 0xFFFFFFFF = invalid
      } else {
        k32 = 0xFFFFFFFFu;  // invalid rows sort last
      }
      key = ((u64)k32 << 32) | (unsigned int)row;
    } else {
      key = ((u64)0xFFFFFFFFu << 32);  // pad
    }
    sk[row] = key;
  }
  __syncthreads();
  for (unsigned int k = 2; k <= NCAP; k <<= 1) {
    for (unsigned int j = k >> 1; j > 0; j >>= 1) {
      for (int t = tid; t < NCAP; t += 1024) {
        unsigned int p = (unsigned int)t ^ j;
        if (p > (unsigned int)t) {
          bool up = ((t & k) == 0);
          u64 x = sk[t], y = sk[p];
          bool sw = up ? (x > y) : (x < y);
          if (sw) { sk[t] = y; sk[p] = x; }
        }
      }
      __syncthreads();
    }
  }
  int cv = 0;
  for (int t = tid; t < NCAP; t += 1024) {
    keys[t] = sk[t];
    if ((sk[t] >> 32) != 0xFFFFFFFFull) ++cv;
  }
  redc[tid] = cv;
  __syncthreads();
  for (int s = 512; s > 0; s >>= 1) {
    if (tid < s) redc[tid] += redc[tid + s];
    __syncthreads();
  }
  if (tid == 0) cnt[0] = (unsigned int)cv + 0 * cv, cnt[0] = (unsigned int)redc[0];
}

// Gather boxes into sorted order, precompute areas.
__global__ void k_gather(const float* __restrict__ loc,
                         const u64* __restrict__ keys,
                         float* __restrict__ sx1, float* __restrict__ sy1,
                         float* __restrict__ sx2, float* __restrict__ sy2,
                         float* __restrict__ sarea, unsigned int* __restrict__ sorig) {
  int p = blockIdx.x * blockDim.x + threadIdx.x;
  if (p >= NCAP) return;
  unsigned int row = (unsigned int)(keys[p] & 0xFFFFFFFFull);
  const float* b = loc + (size_t)row * 4;
  float x1 = b[0], y1 = b[1], x2 = b[2], y2 = b[3];
  sx1[p] = x1; sy1[p] = y1; sx2[p] = x2; sy2[p] = y2;
  sarea[p] = (x2 - x1) * (y2 - y1);   // numpy op order, no FMA hazard
  sorig[p] = row;
}

// Pairwise IoU>0.5 bitmask, torchvision style: 64x64 tiles, 1 wave per block.
// Lower-triangle blocks (by < bx) are never read by k_scan -> skipped.
__global__ __launch_bounds__(64) void k_mask(
    const float* __restrict__ sx1, const float* __restrict__ sy1,
    const float* __restrict__ sx2, const float* __restrict__ sy2,
    const float* __restrict__ sarea,
    u64* __restrict__ mask) {
  if (blockIdx.y < blockIdx.x) return;   // only words >= own chunk are consumed
  __shared__ float jx1[64], jy1[64], jx2[64], jy2[64], ja[64];
  int t = threadIdx.x;
  int jbase = blockIdx.y * 64;
  jx1[t] = sx1[jbase + t]; jy1[t] = sy1[jbase + t];
  jx2[t] = sx2[jbase + t]; jy2[t] = sy2[jbase + t];
  ja[t]  = sarea[jbase + t];
  __syncthreads();
  int i = blockIdx.x * 64 + t;
  float xi1 = sx1[i], yi1 = sy1[i], xi2 = sx2[i], yi2 = sy2[i], ai = sarea[i];
  u64 bits = 0ULL;
#pragma unroll 8
  for (int jj = 0; jj < 64; ++jj) {
    float xx1 = fmaxf(xi1, jx1[jj]);
    float yy1 = fmaxf(yi1, jy1[jj]);
    float xx2 = fminf(xi2, jx2[jj]);
    float yy2 = fminf(yi2, jy2[jj]);
    float w = fmaxf(xx2 - xx1, 0.0f);
    float h = fmaxf(yy2 - yy1, 0.0f);
    float inter = w * h;
    float den = ai + ja[jj] - inter;   // (ai + aj) - inter, numpy order
    float iou = inter / den;           // IEEE div; 0/0 -> NaN -> compare false
    if (iou > 0.5f) bits |= (1ULL << jj);
  }
  mask[(size_t)i * WROW + blockIdx.y] = bits;
}

// ---------------------------------------------------------------------------
// Chunked greedy scan — round-5 version VERBATIM (empirical best: 598 us).
// ONE block of 1024 threads (16 waves). Per 64-row chunk h:
//   phase 1: thread tid loads its 4 linear 16B units of the chunk into
//            registers; holders of diagonal word h publish 64 u64 to ldsD.
//   phase 2: wave 0 resolves the within-chunk greedy (uniform ctz+readlane).
//   phase 3: threads OR their registers into LDS rem[] for KEPT rows only.
// 2 barriers/chunk; rem[] (LDS, 1 KB) is the only persistent state.
// ---------------------------------------------------------------------------
__global__ __launch_bounds__(1024) void k_scan(
    const u64* __restrict__ mask,
    unsigned int* __restrict__ cnt,
    unsigned int* __restrict__ keeps) {
  __shared__ u64 rem[WROW];   // removed-set, bit (64w+b) = sorted row 64w+b dead
  __shared__ u64 ldsD[64];    // diag word h of each chunk row
  __shared__ u64 ldsKeep;
  const int tid = threadIdx.x;
  const int F = (int)cnt[0];
  const int nch = (F + 63) >> 6;
  const ulonglong2* __restrict__ m2 = (const ulonglong2*)mask;  // 64 pairs/row

  for (int w = tid; w < WROW; w += 1024) rem[w] = 0;

  const int p0 = tid & 63;    // pair index (words 2p0, 2p0+1) of each held row
  const int g0 = tid >> 6;    // row group: holds rows g0, g0+16, g0+32, g0+48
  int K = 0;

  for (int h = 0; h < nch; ++h) {
    const size_t gb = (size_t)h * 4096;   // chunk = 4096 linear 16B units
    const bool ld = (2 * p0 + 1) >= h;    // pair relevant iff top word >= h
    ulonglong2 v0 = {0,0}, v1 = {0,0}, v2 = {0,0}, v3 = {0,0};
    if (ld) {
      v0 = m2[gb + tid];
      v1 = m2[gb + tid + 1024];
      v2 = m2[gb + tid + 2048];
      v3 = m2[gb + tid + 3072];
    }
    if (p0 == (h >> 1)) {   // ld is provably true here
      ldsD[g0]      = (h & 1) ? v0.y : v0.x;
      ldsD[g0 + 16] = (h & 1) ? v1.y : v1.x;
      ldsD[g0 + 32] = (h & 1) ? v2.y : v2.x;
      ldsD[g0 + 48] = (h & 1) ? v3.y : v3.x;
    }
    __syncthreads();   // ldsD + prev chunk's rem ORs visible

    if (tid < 64) {
      u64 sup = rem[h];                    // same addr all lanes -> broadcast
      u64 D = ldsD[tid];
      unsigned int Dlo = (unsigned int)D, Dhi = (unsigned int)(D >> 32);
      int remrows = F - (h << 6);
      u64 valid = (remrows >= 64) ? ~0ull : ((1ull << remrows) - 1ull);
      u64 undec = valid & ~sup;            // uniform across wave 0
      u64 keep = 0;
      while (undec) {
        int rr = __builtin_ctzll(undec);   // uniform -> SGPR lane index
        keep |= 1ull << rr;
        unsigned int dlo = __builtin_amdgcn_readlane(Dlo, rr);
        unsigned int dhi = __builtin_amdgcn_readlane(Dhi, rr);
        // clear rr itself too: degenerate boxes can give NaN self-IoU
        undec &= ~(((u64)dhi << 32) | (u64)dlo | (1ull << rr));
      }
      if (tid == 0) {
        ldsKeep = keep;
        u64 kk = keep; int kb = h << 6;
        while (kk) { int rr = __builtin_ctzll(kk); kk &= kk - 1;
                     keeps[K] = (unsigned int)(kb + rr); ++K; }
      }
    }
    __syncthreads();   // ldsKeep visible

    const u64 keep = ldsKeep;
    if (ld && keep) {
      const int w0 = 2 * p0;
      const bool e0 = (w0 >= h);           // low word relevant?
      if ((keep >> g0) & 1ull)        { if (e0) atomicOr(&rem[w0], v0.x); atomicOr(&rem[w0+1], v0.y); }
      if ((keep >> (g0+16)) & 1ull)   { if (e0) atomicOr(&rem[w0], v1.x); atomicOr(&rem[w0+1], v1.y); }
      if ((keep >> (g0+32)) & 1ull)   { if (e0) atomicOr(&rem[w0], v2.x); atomicOr(&rem[w0+1], v2.y); }
      if ((keep >> (g0+48)) & 1ull)   { if (e0) atomicOr(&rem[w0], v3.x); atomicOr(&rem[w0+1], v3.y); }
    }
    // next iteration's first barrier orders these ORs before rem[h+1] read
  }
  if (tid == 0) cnt[1] = (unsigned int)K;
}

// Fallback (small workspace): on-the-fly IoU greedy scan in one block.
__global__ __launch_bounds__(256) void k_scan_nomask(
    const float* __restrict__ sx1, const float* __restrict__ sy1,
    const float* __restrict__ sx2, const float* __restrict__ sy2,
    const float* __restrict__ sarea,
    unsigned int* __restrict__ cnt,
    unsigned int* __restrict__ keeps) {
  __shared__ unsigned char sup[NCAP];
  __shared__ int sK;
  int tid = threadIdx.x;
  int F = (int)cnt[0];
  for (int j = tid; j < NCAP; j += 256) sup[j] = 0;
  if (tid == 0) sK = 0;
  __syncthreads();
  for (int i = 0; i < F; ++i) {
    if (!sup[i]) {
      if (tid == 0) keeps[sK++] = (unsigned int)i;
      float xi1 = sx1[i], yi1 = sy1[i], xi2 = sx2[i], yi2 = sy2[i], ai = sarea[i];
      for (int j = i + 1 + tid; j < F; j += 256) {
        if (sup[j]) continue;
        float xx1 = fmaxf(xi1, sx1[j]);
        float yy1 = fmaxf(yi1, sy1[j]);
        float xx2 = fminf(xi2, sx2[j]);
        float yy2 = fminf(yi2, sy2[j]);
        float w = fmaxf(xx2 - xx1, 0.0f);
        float h = fmaxf(yy2 - yy1, 0.0f);
        float inter = w * h;
        float iou = inter / (ai + sarea[j] - inter);
        if (iou > 0.5f) sup[j] = 1;
      }
    }
    __syncthreads();
  }
  if (tid == 0) cnt[1] = (unsigned int)sK;
}

// Per class (block), top-KT over the M kept boxes; lax.top_k tie semantics
// (descending value, lower index wins ties). korig dispatch eliminated:
// kept -> orig row resolved inline via sorig[keeps[j]].
// Reduction: 64-lane shuffle + one cross-wave LDS step (2 barriers/iter,
// was 10 with the tree reduce). Selection is a total order -> result is
// reduction-shape independent.
__global__ __launch_bounds__(256) void k_topk(
    const float* __restrict__ conf,
    const unsigned int* __restrict__ sorig,
    const unsigned int* __restrict__ keeps,
    const unsigned int* __restrict__ cnt,
    int C, int KT,
    float* __restrict__ topv, int* __restrict__ topi) {
  __shared__ float col[NCAP];
  __shared__ unsigned char flags[NCAP];
  __shared__ float wrv[4];
  __shared__ int wri[4];
  int tid = threadIdx.x;
  int c = blockIdx.x;
  int M = (int)cnt[1];
  for (int j = tid; j < M; j += 256) {
    col[j] = conf[(size_t)sorig[keeps[j]] * C + c];
    flags[j] = 0;
  }
  __syncthreads();
  for (int t = 0; t < KT; ++t) {
    float bv = -3.402823466e+38f;
    int bj = 0x7FFFFFFF;
    for (int j = tid; j < M; j += 256) {
      if (flags[j]) continue;
      float v = col[j];
      if (v > bv || (v == bv && j < bj)) { bv = v; bj = j; }
    }
    // 64-lane shuffle reduce, no barriers
    for (int off = 32; off > 0; off >>= 1) {
      float v2 = __shfl_down(bv, off);
      int   j2 = __shfl_down(bj, off);
      if (v2 > bv || (v2 == bv && j2 < bj)) { bv = v2; bj = j2; }
    }
    if ((tid & 63) == 0) { wrv[tid >> 6] = bv; wri[tid >> 6] = bj; }
    __syncthreads();
    if (tid == 0) {
      bv = wrv[0]; bj = wri[0];
#pragma unroll
      for (int wv = 1; wv < 4; ++wv) {
        float v2 = wrv[wv]; int j2 = wri[wv];
        if (v2 > bv || (v2 == bv && j2 < bj)) { bv = v2; bj = j2; }
      }
      int w = bj;
      if (w == 0x7FFFFFFF) w = 0;    // M < KT safety; reference would crash here
      else flags[w] = 1;
      topv[c * KT + t] = bv;
      topi[c * KT + t] = w;
    }
    __syncthreads();
  }
}

// Final scalar: smooth-L1 over (KT, C, 4) gathered boxes + focal CE on
// (class0 top-KT > 0.5), divided by M. korig resolved via sorig[keeps[.]].
__global__ __launch_bounds__(256) void k_loss(
    const float* __restrict__ loc, const float* __restrict__ tb,
    const int* __restrict__ labels,
    const unsigned int* __restrict__ sorig,
    const unsigned int* __restrict__ keeps,
    const float* __restrict__ topv, const int* __restrict__ topi,
    const unsigned int* __restrict__ cnt, int C, int KT,
    float* __restrict__ out) {
  __shared__ float red[256];
  int tid = threadIdx.x;
  int F = (int)cnt[0];
  int M = (int)cnt[1];
  if (F == 0 || M == 0) {
    if (tid == 0) out[0] = 0.001f;
    return;
  }
  int total = KT * C * 4;
  float part = 0.0f;
  for (int e = tid; e < total; e += 256) {
    int d = e & 3;
    int q = e >> 2;
    int c = q % C;
    int i = q / C;
    int j = topi[c * KT + i];
    unsigned int orow = sorig[keeps[j]];
    float pred = loc[(size_t)orow * 4 + d];
    float tg = tb[c * 4 + d];
    float dd = fabsf(pred - tg);
    part += (dd < 1.0f) ? (0.5f * dd * dd) : (dd - 0.5f);
  }
  red[tid] = part;
  __syncthreads();
  for (int s = 128; s > 0; s >>= 1) {
    if (tid < s) red[tid] += red[tid + s];
    __syncthreads();
  }
  if (tid == 0) {
    float loc_loss = red[0];
    float mx = -3.402823466e+38f;
    for (int i = 0; i < KT; ++i) {
      float x = (topv[i] > 0.5f) ? 1.0f : 0.0f;   // class 0 column
      mx = fmaxf(mx, x);
    }
    float ssum = 0.0f;
    for (int i = 0; i < KT; ++i) {
      float x = (topv[i] > 0.5f) ? 1.0f : 0.0f;
      ssum += expf(x - mx);
    }
    float lse = mx + logf(ssum);
    float ce = 0.0f;
    for (int i = 0; i < KT; ++i) {
      float x = (topv[i] > 0.5f) ? 1.0f : 0.0f;
      ce += (float)labels[i] * (x - lse);
    }
    ce = -ce;
    float pt = expf(-ce);
    float om = 1.0f - pt;
    float conf_loss = 0.25f * om * om * ce;   // ALPHA=0.25, GAMMA=2
    out[0] = (loc_loss + conf_loss) / (float)M;
  }
}

// ---------------- host ------------------------------------------------------

extern "C" void kernel_launch(void* const* d_in, const int* in_sizes, int n_in,
                              void* d_out, int out_size, void* d_ws, size_t ws_size,
                              hipStream_t stream) {
  (void)n_in; (void)out_size;
  const float* loc    = (const float*)d_in[0];
  const float* conf   = (const float*)d_in[1];
  const float* tb     = (const float*)d_in[2];
  const int*   labels = (const int*)d_in[3];
  float* out = (float*)d_out;

  int N = in_sizes[0] / 4;
  if (N > NCAP) N = NCAP;
  int C  = (N > 0) ? (in_sizes[1] / N) : 20;
  int KT = in_sizes[3];

  char* ws = (char*)d_ws;
  unsigned int* cnt   = (unsigned int*)(ws + OFF_CNT);
  u64*          keys  = (u64*)(ws + OFF_KEYS);
  float*        sx1   = (float*)(ws + OFF_SX1);
  float*        sy1   = (float*)(ws + OFF_SY1);
  float*        sx2   = (float*)(ws + OFF_SX2);
  float*        sy2   = (float*)(ws + OFF_SY2);
  float*        sarea = (float*)(ws + OFF_AREA);
  unsigned int* sorig = (unsigned int*)(ws + OFF_SORIG);
  unsigned int* keeps = (unsigned int*)(ws + OFF_KEEPS);
  float*        topv  = (float*)(ws + OFF_TOPV);
  int*          topi  = (int*)(ws + OFF_TOPI);
  u64*          mask  = (u64*)(ws + OFF_MASK);

  bool use_mask = (ws_size >= WS_NEED_MASK);

  k_sortf<<<1, 1024, 0, stream>>>(conf, N, C, keys, cnt);
  k_gather<<<NCAP / 256, 256, 0, stream>>>(loc, keys, sx1, sy1, sx2, sy2, sarea, sorig);
  if (use_mask) {
    k_mask<<<dim3(WROW, WROW), 64, 0, stream>>>(sx1, sy1, sx2, sy2, sarea, mask);
    k_scan<<<1, 1024, 0, stream>>>(mask, cnt, keeps);
  } else {
    k_scan_nomask<<<1, 256, 0, stream>>>(sx1, sy1, sx2, sy2, sarea, cnt, keeps);
  }
  k_topk<<<C, 256, 0, stream>>>(conf, sorig, keeps, cnt, C, KT, topv, topi);
  k_loss<<<1, 256, 0, stream>>>(loc, tb, labels, sorig, keeps, topv, topi, cnt, C, KT, out);
}

// Round 10
// 570.033 us; speedup vs baseline: 2.6372x; 1.7083x over previous
//
#include <hip/hip_runtime.h>
#include <stdint.h>
#include <stddef.h>

// ---------------------------------------------------------------------------
// BoundingBox loss processor:
//   filter (maxconf > 0.6) -> sort by class-0 score desc (stable, idx asc)
//   -> greedy NMS (IoU > 0.5 suppress) -> per-class top-20 over kept
//   -> smooth-L1 vs targets + focal CE on (class0 top-20 > 0.5) -> /M
//
// Rounds 1-9 findings: k_scan serial chain dominates. With uniform random
// boxes most are degenerate -> suppression RARE, M ~ F ~ 8000 -> the per-keep
// ctz/readlane chain (~8000 iters) is the ~600 us floor, not memory. This
// round: involved-set shortcut — rows with no within-chunk conflicts are kept
// lane-parallel; the chain runs only over conflicted rows (~few per chunk).
// ---------------------------------------------------------------------------

#define NCAP 8192
#define WROW (NCAP / 64)   // 128 u64 words per mask row

typedef unsigned long long u64;

// ---------------- workspace layout (all offsets 16-byte aligned) -----------
constexpr size_t OFF_CNT   = 0;                               // 2 x u32: [0]=F, [1]=M
constexpr size_t OFF_KEYS  = 256;                             // u64[NCAP]
constexpr size_t OFF_SX1   = OFF_KEYS + 8ull * NCAP;          // f32[NCAP]
constexpr size_t OFF_SY1   = OFF_SX1 + 4ull * NCAP;
constexpr size_t OFF_SX2   = OFF_SY1 + 4ull * NCAP;
constexpr size_t OFF_SY2   = OFF_SX2 + 4ull * NCAP;
constexpr size_t OFF_AREA  = OFF_SY2 + 4ull * NCAP;
constexpr size_t OFF_SORIG = OFF_AREA + 4ull * NCAP;          // u32[NCAP]
constexpr size_t OFF_KEEPS = OFF_SORIG + 4ull * NCAP;         // u32[NCAP]
constexpr size_t OFF_KORIG = OFF_KEEPS + 4ull * NCAP;         // u32[NCAP] (unused)
constexpr size_t OFF_TOPV  = OFF_KORIG + 4ull * NCAP;         // f32[1024]
constexpr size_t OFF_TOPI  = OFF_TOPV + 4096;                 // i32[1024]
constexpr size_t OFF_MASK  = OFF_TOPI + 4096;                 // u64[NCAP*WROW] = 8 MB
constexpr size_t WS_NEED_MASK = OFF_MASK + 8ull * NCAP * WROW;

// wave-wide OR of a u64 (6 butterfly steps, 2x32b shuffles each)
__device__ __forceinline__ u64 wave_or64(u64 x) {
#pragma unroll
  for (int off = 1; off < 64; off <<= 1) {
    unsigned lo = __shfl_xor((unsigned)x, off);
    unsigned hi = __shfl_xor((unsigned)(x >> 32), off);
    x |= ((u64)hi << 32) | lo;
  }
  return x;
}

// ---------------- kernels ---------------------------------------------------

// Fused filter + one-block LDS bitonic sort, ascending u64
// (desc class-0 score, asc row on ties). Epilogue counts valid rows -> cnt[0].
__global__ __launch_bounds__(1024) void k_sortf(
    const float* __restrict__ conf, int N, int C,
    u64* __restrict__ keys, unsigned int* __restrict__ cnt) {
  __shared__ u64 sk[NCAP];  // 64 KiB
  __shared__ int redc[1024];
  int tid = threadIdx.x;
  for (int row = tid; row < NCAP; row += 1024) {
    u64 key;
    if (row < N) {
      const float* cr = conf + (size_t)row * C;
      float mx = cr[0];
      for (int c = 1; c < C; ++c) mx = fmaxf(mx, cr[c]);
      unsigned int k32;
      if (mx > 0.6f) {
        union { float f; unsigned int u; } s; s.f = cr[0];
        unsigned int u = s.u;
        // monotone float->uint (ascending), then invert for descending sort
        u = (u & 0x80000000u) ? ~u : (u | 0x80000000u);
        k32 = ~u;
        if (k32 == 0xFFFFFFFFu) k32 = 0xFFFFFFFEu;  // 0xFFFFFFFF = invalid
      } else {
        k32 = 0xFFFFFFFFu;  // invalid rows sort last
      }
      key = ((u64)k32 << 32) | (unsigned int)row;
    } else {
      key = ((u64)0xFFFFFFFFu << 32);  // pad
    }
    sk[row] = key;
  }
  __syncthreads();
  for (unsigned int k = 2; k <= NCAP; k <<= 1) {
    for (unsigned int j = k >> 1; j > 0; j >>= 1) {
      for (int t = tid; t < NCAP; t += 1024) {
        unsigned int p = (unsigned int)t ^ j;
        if (p > (unsigned int)t) {
          bool up = ((t & k) == 0);
          u64 x = sk[t], y = sk[p];
          bool sw = up ? (x > y) : (x < y);
          if (sw) { sk[t] = y; sk[p] = x; }
        }
      }
      __syncthreads();
    }
  }
  int cv = 0;
  for (int t = tid; t < NCAP; t += 1024) {
    keys[t] = sk[t];
    if ((sk[t] >> 32) != 0xFFFFFFFFull) ++cv;
  }
  redc[tid] = cv;
  __syncthreads();
  for (int s = 512; s > 0; s >>= 1) {
    if (tid < s) redc[tid] += redc[tid + s];
    __syncthreads();
  }
  if (tid == 0) cnt[0] = (unsigned int)redc[0];
}

// Gather boxes into sorted order, precompute areas.
__global__ void k_gather(const float* __restrict__ loc,
                         const u64* __restrict__ keys,
                         float* __restrict__ sx1, float* __restrict__ sy1,
                         float* __restrict__ sx2, float* __restrict__ sy2,
                         float* __restrict__ sarea, unsigned int* __restrict__ sorig) {
  int p = blockIdx.x * blockDim.x + threadIdx.x;
  if (p >= NCAP) return;
  unsigned int row = (unsigned int)(keys[p] & 0xFFFFFFFFull);
  const float* b = loc + (size_t)row * 4;
  float x1 = b[0], y1 = b[1], x2 = b[2], y2 = b[3];
  sx1[p] = x1; sy1[p] = y1; sx2[p] = x2; sy2[p] = y2;
  sarea[p] = (x2 - x1) * (y2 - y1);   // numpy op order, no FMA hazard
  sorig[p] = row;
}

// Pairwise IoU>0.5 bitmask, torchvision style: 64x64 tiles, 1 wave per block.
// Lower-triangle blocks (by < bx) are never read by k_scan -> skipped.
__global__ __launch_bounds__(64) void k_mask(
    const float* __restrict__ sx1, const float* __restrict__ sy1,
    const float* __restrict__ sx2, const float* __restrict__ sy2,
    const float* __restrict__ sarea,
    u64* __restrict__ mask) {
  if (blockIdx.y < blockIdx.x) return;   // only words >= own chunk are consumed
  __shared__ float jx1[64], jy1[64], jx2[64], jy2[64], ja[64];
  int t = threadIdx.x;
  int jbase = blockIdx.y * 64;
  jx1[t] = sx1[jbase + t]; jy1[t] = sy1[jbase + t];
  jx2[t] = sx2[jbase + t]; jy2[t] = sy2[jbase + t];
  ja[t]  = sarea[jbase + t];
  __syncthreads();
  int i = blockIdx.x * 64 + t;
  float xi1 = sx1[i], yi1 = sy1[i], xi2 = sx2[i], yi2 = sy2[i], ai = sarea[i];
  u64 bits = 0ULL;
#pragma unroll 8
  for (int jj = 0; jj < 64; ++jj) {
    float xx1 = fmaxf(xi1, jx1[jj]);
    float yy1 = fmaxf(yi1, jy1[jj]);
    float xx2 = fminf(xi2, jx2[jj]);
    float yy2 = fminf(yi2, jy2[jj]);
    float w = fmaxf(xx2 - xx1, 0.0f);
    float h = fmaxf(yy2 - yy1, 0.0f);
    float inter = w * h;
    float den = ai + ja[jj] - inter;   // (ai + aj) - inter, numpy order
    float iou = inter / den;           // IEEE div; 0/0 -> NaN -> compare false
    if (iou > 0.5f) bits |= (1ULL << jj);
  }
  mask[(size_t)i * WROW + blockIdx.y] = bits;
}

// ---------------------------------------------------------------------------
// Chunked greedy scan — round-5 structure (memory phases verbatim) with the
// phase-2 greedy replaced by the involved-set shortcut:
//   Dfwd[r] = forward-only within-chunk suppressions of row r.
//   dang    = rows (undec) that threaten someone;  vuln = OR of their targets.
//   rows undec & ~(dang|vuln): kept instantly, no serial step (they target
//   nobody and nobody targets them — the overwhelming majority here).
//   chain runs only over involved = (dang|vuln) & undec (~few rows).
// Keep-set provably identical to the full greedy; chain iters strictly <= old.
// keeps[] store parallelized via mbcnt prefix (was serial in lane 0).
// ---------------------------------------------------------------------------
__global__ __launch_bounds__(1024) void k_scan(
    const u64* __restrict__ mask,
    unsigned int* __restrict__ cnt,
    unsigned int* __restrict__ keeps) {
  __shared__ u64 rem[WROW];   // removed-set, bit (64w+b) = sorted row 64w+b dead
  __shared__ u64 ldsD[64];    // diag word h of each chunk row
  __shared__ u64 ldsKeep;
  const int tid = threadIdx.x;
  const int F = (int)cnt[0];
  const int nch = (F + 63) >> 6;
  const ulonglong2* __restrict__ m2 = (const ulonglong2*)mask;  // 64 pairs/row

  for (int w = tid; w < WROW; w += 1024) rem[w] = 0;

  const int p0 = tid & 63;    // pair index (words 2p0, 2p0+1) of each held row
  const int g0 = tid >> 6;    // row group: holds rows g0, g0+16, g0+32, g0+48
  int K = 0;

  for (int h = 0; h < nch; ++h) {
    const size_t gb = (size_t)h * 4096;   // chunk = 4096 linear 16B units
    const bool ld = (2 * p0 + 1) >= h;    // pair relevant iff top word >= h
    ulonglong2 v0 = {0,0}, v1 = {0,0}, v2 = {0,0}, v3 = {0,0};
    if (ld) {
      v0 = m2[gb + tid];
      v1 = m2[gb + tid + 1024];
      v2 = m2[gb + tid + 2048];
      v3 = m2[gb + tid + 3072];
    }
    if (p0 == (h >> 1)) {   // ld is provably true here
      ldsD[g0]      = (h & 1) ? v0.y : v0.x;
      ldsD[g0 + 16] = (h & 1) ? v1.y : v1.x;
      ldsD[g0 + 32] = (h & 1) ? v2.y : v2.x;
      ldsD[g0 + 48] = (h & 1) ? v3.y : v3.x;
    }
    __syncthreads();   // ldsD + prev chunk's rem ORs visible

    if (tid < 64) {
      u64 sup = rem[h];                    // same addr all lanes -> broadcast
      u64 D = ldsD[tid];
      // forward-only suppressions (greedy: kept r suppresses only j > r;
      // also drops any NaN self-bit)
      u64 Dfwd = (tid < 63) ? (D & (~0ull << (tid + 1))) : 0ull;
      int remrows = F - (h << 6);
      u64 valid = (remrows >= 64) ? ~0ull : ((1ull << remrows) - 1ull);
      u64 undec = valid & ~sup;            // uniform across wave 0
      // rows that could suppress someone (only undec rows can ever be kept)
      u64 dmask = ((undec >> tid) & 1ull) ? Dfwd : 0ull;
      u64 vuln = wave_or64(dmask);         // all threatened columns
      u64 dang = __ballot(dmask != 0ull);  // all threatening rows
      u64 involved = (dang | vuln) & undec;
      u64 keep = undec & ~involved;        // conflict-free rows: kept instantly
      u64 und2 = involved;
      unsigned Flo = (unsigned)Dfwd, Fhi = (unsigned)(Dfwd >> 32);
      while (und2) {
        int rr = __builtin_ctzll(und2);    // uniform -> SGPR lane index
        keep |= 1ull << rr;
        unsigned dlo = __builtin_amdgcn_readlane(Flo, rr);
        unsigned dhi = __builtin_amdgcn_readlane(Fhi, rr);
        und2 &= ~((((u64)dhi << 32) | (u64)dlo) | (1ull << rr));
      }
      if (tid == 0) ldsKeep = keep;
      // parallel keeps store, ascending order via mbcnt prefix
      unsigned klo = (unsigned)keep, khi = (unsigned)(keep >> 32);
      int pre = __builtin_amdgcn_mbcnt_hi(khi, __builtin_amdgcn_mbcnt_lo(klo, 0));
      if ((keep >> tid) & 1ull) keeps[K + pre] = (unsigned)((h << 6) + tid);
      K += __popcll(keep);
    }
    __syncthreads();   // ldsKeep visible

    const u64 keep = ldsKeep;
    if (ld && keep) {
      const int w0 = 2 * p0;
      const bool e0 = (w0 >= h);           // low word relevant?
      if ((keep >> g0) & 1ull)        { if (e0) atomicOr(&rem[w0], v0.x); atomicOr(&rem[w0+1], v0.y); }
      if ((keep >> (g0+16)) & 1ull)   { if (e0) atomicOr(&rem[w0], v1.x); atomicOr(&rem[w0+1], v1.y); }
      if ((keep >> (g0+32)) & 1ull)   { if (e0) atomicOr(&rem[w0], v2.x); atomicOr(&rem[w0+1], v2.y); }
      if ((keep >> (g0+48)) & 1ull)   { if (e0) atomicOr(&rem[w0], v3.x); atomicOr(&rem[w0+1], v3.y); }
    }
    // next iteration's first barrier orders these ORs before rem[h+1] read
  }
  if (tid == 0) cnt[1] = (unsigned int)K;
}

// Fallback (small workspace): on-the-fly IoU greedy scan in one block.
__global__ __launch_bounds__(256) void k_scan_nomask(
    const float* __restrict__ sx1, const float* __restrict__ sy1,
    const float* __restrict__ sx2, const float* __restrict__ sy2,
    const float* __restrict__ sarea,
    unsigned int* __restrict__ cnt,
    unsigned int* __restrict__ keeps) {
  __shared__ unsigned char sup[NCAP];
  __shared__ int sK;
  int tid = threadIdx.x;
  int F = (int)cnt[0];
  for (int j = tid; j < NCAP; j += 256) sup[j] = 0;
  if (tid == 0) sK = 0;
  __syncthreads();
  for (int i = 0; i < F; ++i) {
    if (!sup[i]) {
      if (tid == 0) keeps[sK++] = (unsigned int)i;
      float xi1 = sx1[i], yi1 = sy1[i], xi2 = sx2[i], yi2 = sy2[i], ai = sarea[i];
      for (int j = i + 1 + tid; j < F; j += 256) {
        if (sup[j]) continue;
        float xx1 = fmaxf(xi1, sx1[j]);
        float yy1 = fmaxf(yi1, sy1[j]);
        float xx2 = fminf(xi2, sx2[j]);
        float yy2 = fminf(yi2, sy2[j]);
        float w = fmaxf(xx2 - xx1, 0.0f);
        float h = fmaxf(yy2 - yy1, 0.0f);
        float inter = w * h;
        float iou = inter / (ai + sarea[j] - inter);
        if (iou > 0.5f) sup[j] = 1;
      }
    }
    __syncthreads();
  }
  if (tid == 0) cnt[1] = (unsigned int)sK;
}

// Per class (block), top-KT over the M kept boxes; lax.top_k tie semantics
// (descending value, lower index wins ties). kept -> orig row resolved inline
// via sorig[keeps[j]]. 64-lane shuffle reduce + one cross-wave LDS step.
__global__ __launch_bounds__(256) void k_topk(
    const float* __restrict__ conf,
    const unsigned int* __restrict__ sorig,
    const unsigned int* __restrict__ keeps,
    const unsigned int* __restrict__ cnt,
    int C, int KT,
    float* __restrict__ topv, int* __restrict__ topi) {
  __shared__ float col[NCAP];
  __shared__ unsigned char flags[NCAP];
  __shared__ float wrv[4];
  __shared__ int wri[4];
  int tid = threadIdx.x;
  int c = blockIdx.x;
  int M = (int)cnt[1];
  for (int j = tid; j < M; j += 256) {
    col[j] = conf[(size_t)sorig[keeps[j]] * C + c];
    flags[j] = 0;
  }
  __syncthreads();
  for (int t = 0; t < KT; ++t) {
    float bv = -3.402823466e+38f;
    int bj = 0x7FFFFFFF;
    for (int j = tid; j < M; j += 256) {
      if (flags[j]) continue;
      float v = col[j];
      if (v > bv || (v == bv && j < bj)) { bv = v; bj = j; }
    }
    for (int off = 32; off > 0; off >>= 1) {
      float v2 = __shfl_down(bv, off);
      int   j2 = __shfl_down(bj, off);
      if (v2 > bv || (v2 == bv && j2 < bj)) { bv = v2; bj = j2; }
    }
    if ((tid & 63) == 0) { wrv[tid >> 6] = bv; wri[tid >> 6] = bj; }
    __syncthreads();
    if (tid == 0) {
      bv = wrv[0]; bj = wri[0];
#pragma unroll
      for (int wv = 1; wv < 4; ++wv) {
        float v2 = wrv[wv]; int j2 = wri[wv];
        if (v2 > bv || (v2 == bv && j2 < bj)) { bv = v2; bj = j2; }
      }
      int w = bj;
      if (w == 0x7FFFFFFF) w = 0;    // M < KT safety; reference would crash here
      else flags[w] = 1;
      topv[c * KT + t] = bv;
      topi[c * KT + t] = w;
    }
    __syncthreads();
  }
}

// Final scalar: smooth-L1 over (KT, C, 4) gathered boxes + focal CE on
// (class0 top-KT > 0.5), divided by M.
__global__ __launch_bounds__(256) void k_loss(
    const float* __restrict__ loc, const float* __restrict__ tb,
    const int* __restrict__ labels,
    const unsigned int* __restrict__ sorig,
    const unsigned int* __restrict__ keeps,
    const float* __restrict__ topv, const int* __restrict__ topi,
    const unsigned int* __restrict__ cnt, int C, int KT,
    float* __restrict__ out) {
  __shared__ float red[256];
  int tid = threadIdx.x;
  int F = (int)cnt[0];
  int M = (int)cnt[1];
  if (F == 0 || M == 0) {
    if (tid == 0) out[0] = 0.001f;
    return;
  }
  int total = KT * C * 4;
  float part = 0.0f;
  for (int e = tid; e < total; e += 256) {
    int d = e & 3;
    int q = e >> 2;
    int c = q % C;
    int i = q / C;
    int j = topi[c * KT + i];
    unsigned int orow = sorig[keeps[j]];
    float pred = loc[(size_t)orow * 4 + d];
    float tg = tb[c * 4 + d];
    float dd = fabsf(pred - tg);
    part += (dd < 1.0f) ? (0.5f * dd * dd) : (dd - 0.5f);
  }
  red[tid] = part;
  __syncthreads();
  for (int s = 128; s > 0; s >>= 1) {
    if (tid < s) red[tid] += red[tid + s];
    __syncthreads();
  }
  if (tid == 0) {
    float loc_loss = red[0];
    float mx = -3.402823466e+38f;
    for (int i = 0; i < KT; ++i) {
      float x = (topv[i] > 0.5f) ? 1.0f : 0.0f;   // class 0 column
      mx = fmaxf(mx, x);
    }
    float ssum = 0.0f;
    for (int i = 0; i < KT; ++i) {
      float x = (topv[i] > 0.5f) ? 1.0f : 0.0f;
      ssum += expf(x - mx);
    }
    float lse = mx + logf(ssum);
    float ce = 0.0f;
    for (int i = 0; i < KT; ++i) {
      float x = (topv[i] > 0.5f) ? 1.0f : 0.0f;
      ce += (float)labels[i] * (x - lse);
    }
    ce = -ce;
    float pt = expf(-ce);
    float om = 1.0f - pt;
    float conf_loss = 0.25f * om * om * ce;   // ALPHA=0.25, GAMMA=2
    out[0] = (loc_loss + conf_loss) / (float)M;
  }
}

// ---------------- host ------------------------------------------------------

extern "C" void kernel_launch(void* const* d_in, const int* in_sizes, int n_in,
                              void* d_out, int out_size, void* d_ws, size_t ws_size,
                              hipStream_t stream) {
  (void)n_in; (void)out_size;
  const float* loc    = (const float*)d_in[0];
  const float* conf   = (const float*)d_in[1];
  const float* tb     = (const float*)d_in[2];
  const int*   labels = (const int*)d_in[3];
  float* out = (float*)d_out;

  int N = in_sizes[0] / 4;
  if (N > NCAP) N = NCAP;
  int C  = (N > 0) ? (in_sizes[1] / N) : 20;
  int KT = in_sizes[3];

  char* ws = (char*)d_ws;
  unsigned int* cnt   = (unsigned int*)(ws + OFF_CNT);
  u64*          keys  = (u64*)(ws + OFF_KEYS);
  float*        sx1   = (float*)(ws + OFF_SX1);
  float*        sy1   = (float*)(ws + OFF_SY1);
  float*        sx2   = (float*)(ws + OFF_SX2);
  float*        sy2   = (float*)(ws + OFF_SY2);
  float*        sarea = (float*)(ws + OFF_AREA);
  unsigned int* sorig = (unsigned int*)(ws + OFF_SORIG);
  unsigned int* keeps = (unsigned int*)(ws + OFF_KEEPS);
  float*        topv  = (float*)(ws + OFF_TOPV);
  int*          topi  = (int*)(ws + OFF_TOPI);
  u64*          mask  = (u64*)(ws + OFF_MASK);

  bool use_mask = (ws_size >= WS_NEED_MASK);

  k_sortf<<<1, 1024, 0, stream>>>(conf, N, C, keys, cnt);
  k_gather<<<NCAP / 256, 256, 0, stream>>>(loc, keys, sx1, sy1, sx2, sy2, sarea, sorig);
  if (use_mask) {
    k_mask<<<dim3(WROW, WROW), 64, 0, stream>>>(sx1, sy1, sx2, sy2, sarea, mask);
    k_scan<<<1, 1024, 0, stream>>>(mask, cnt, keeps);
  } else {
    k_scan_nomask<<<1, 256, 0, stream>>>(sx1, sy1, sx2, sy2, sarea, cnt, keeps);
  }
  k_topk<<<C, 256, 0, stream>>>(conf, sorig, keeps, cnt, C, KT, topv, topi);
  k_loss<<<1, 256, 0, stream>>>(loc, tb, labels, sorig, keeps, topv, topi, cnt, C, KT, out);
}